// Round 18
// baseline (125.224 us; speedup 1.0000x reference)
//
#include <hip/hip_runtime.h>
#include <cstdint>
#include <cstddef>

typedef __bf16 bf16;
typedef __bf16 bf16x2 __attribute__((ext_vector_type(2)));
typedef __bf16 bf16x4 __attribute__((ext_vector_type(4)));
typedef __bf16 bf16x8 __attribute__((ext_vector_type(8)));
typedef float  f32x4  __attribute__((ext_vector_type(4)));
typedef float  f32x16 __attribute__((ext_vector_type(16)));
typedef int    i32x4  __attribute__((ext_vector_type(4)));

// raw 2^x (v_exp_f32, TRANS pipe, 1 instruction)
__device__ __forceinline__ float fexp2(float x) {
  float r;
  asm("v_exp_f32 %0, %1" : "=v"(r) : "v"(x));
  return r;
}
__device__ __forceinline__ float m3(float a, float b, float c) {
  return fmaxf(fmaxf(a, b), c);   // clang fuses to v_max3_f32
}

// global -> LDS direct (16B/lane, dest = wave-uniform base + lane*16)
#define G2L(src, dst)                                                          \
  __builtin_amdgcn_global_load_lds(                                            \
      (const __attribute__((address_space(1))) unsigned int*)(src),            \
      (__attribute__((address_space(3))) unsigned int*)(dst), 16, 0, 0)

// ---------------- fused prep: x convert (0..2047) + rope tables (2048..2303)
//                  + weight transposes (2304..6399) ----------------
__global__ void k_prep(const float* __restrict__ x, bf16* __restrict__ xb,
                       float* __restrict__ cosT, float* __restrict__ sinT,
                       const float* __restrict__ wqkv, bf16* __restrict__ wqkvt,
                       const float* __restrict__ wproj, bf16* __restrict__ wprojt) {
  __shared__ float tile[32][33];
  int bx = blockIdx.x;
  if (bx < 2048) {
    int i = (bx * 256 + threadIdx.x) * 8;
    float4 a = *(const float4*)(x + i);
    float4 b = *(const float4*)(x + i + 4);
    bf16x8 o;
    o[0] = (bf16)a.x; o[1] = (bf16)a.y; o[2] = (bf16)a.z; o[3] = (bf16)a.w;
    o[4] = (bf16)b.x; o[5] = (bf16)b.y; o[6] = (bf16)b.z; o[7] = (bf16)b.w;
    *(bf16x8*)(xb + i) = o;
  } else if (bx < 2304) {
    int i = (bx - 2048) * 256 + threadIdx.x;   // 0..65535
    int t = i >> 5, j = i & 31;
    float inv = powf(10000.0f, -(float)j * (1.0f / 32.0f));
    float f = (float)t * inv;
    cosT[i] = cosf(f);
    sinT[i] = sinf(f);
  } else {
    int tb = bx - 2304;              // 0..4095
    int ty = tb >> 7, tx = tb & 127;
    const float* in;
    bf16* out;
    int C;
    if (tx < 96) { in = wqkv; out = wqkvt; C = 3072; }
    else         { in = wproj; out = wprojt; C = 1024; tx -= 96; }
    const int R = 1024;
    int c0 = tx * 32, r0 = ty * 32;
    int lx = threadIdx.x & 31, ly = threadIdx.x >> 5;  // 32 x 8
#pragma unroll
    for (int i = 0; i < 32; i += 8)
      tile[ly + i][lx] = in[(size_t)(r0 + ly + i) * C + c0 + lx];
    __syncthreads();
#pragma unroll
    for (int i = 0; i < 32; i += 8)
      out[(size_t)(c0 + ly + i) * R + r0 + lx] = (bf16)tile[lx][ly + i];
  }
}

// ---------------- fused RoPE(q,k) + V-transpose: one pass over qkv ----------------
__global__ __launch_bounds__(256) void k_rope_v(const bf16* __restrict__ qkv,
                                                const float* __restrict__ cosT,
                                                const float* __restrict__ sinT,
                                                bf16* __restrict__ qr,
                                                bf16* __restrict__ kr,
                                                bf16* __restrict__ vt) {
  __shared__ bf16 tile[64][66];
  int bh = blockIdx.y;           // 0..31
  int t0 = blockIdx.x * 64;
  int b = bh >> 4, h = bh & 15;
  int tt = threadIdx.x >> 2, g = threadIdx.x & 3;
  int c4 = g * 16;
  const bf16* row = qkv + (size_t)(b * 2048 + t0 + tt) * 3072 + h * 64;
  bf16x8 v0 = *(const bf16x8*)(row + 2048 + c4);
  bf16x8 v1 = *(const bf16x8*)(row + 2048 + c4 + 8);
#pragma unroll
  for (int j = 0; j < 8; j++) { tile[tt][c4 + j] = v0[j]; tile[tt][c4 + 8 + j] = v1[j]; }
  int tglob = t0 + tt;
  size_t ob = ((size_t)bh * 2048 + tglob) * 64;
  const float QS = 0.125f * 1.44269504f;
  bf16x8 qlo = *(const bf16x8*)(row + g * 8);
  bf16x8 qhi = *(const bf16x8*)(row + 32 + g * 8);
  bf16x8 klo = *(const bf16x8*)(row + 1024 + g * 8);
  bf16x8 khi = *(const bf16x8*)(row + 1024 + 32 + g * 8);
  bf16x8 qo0, qo1, ko0, ko1;
#pragma unroll
  for (int j = 0; j < 8; j++) {
    float c = cosT[tglob * 32 + g * 8 + j], s = sinT[tglob * 32 + g * 8 + j];
    float ql = (float)qlo[j], qh = (float)qhi[j];
    float kl = (float)klo[j], kh = (float)khi[j];
    qo0[j] = (bf16)((ql * c - qh * s) * QS);
    qo1[j] = (bf16)((qh * c + ql * s) * QS);
    ko0[j] = (bf16)(kl * c - kh * s);
    ko1[j] = (bf16)(kh * c + kl * s);
  }
  *(bf16x8*)&qr[ob + g * 8]      = qo0;
  *(bf16x8*)&qr[ob + 32 + g * 8] = qo1;
  *(bf16x8*)&kr[ob + g * 8]      = ko0;
  *(bf16x8*)&kr[ob + 32 + g * 8] = ko1;
  __syncthreads();
  int d = threadIdx.x >> 2, tc0 = (threadIdx.x & 3) * 16;
  bf16x8 o0, o1;
#pragma unroll
  for (int j = 0; j < 8; j++) { o0[j] = tile[tc0 + j][d]; o1[j] = tile[tc0 + 8 + j][d]; }
  bf16* dst = vt + ((size_t)bh * 64 + d) * 2048 + t0 + tc0;
  *(bf16x8*)dst = o0;
  *(bf16x8*)(dst + 8) = o1;
}

// ---------------- GEMM 128x128 (m97 structure + XCD swizzle): C = A * Bt^T ----------------
template <int OUTF32>
__global__ __launch_bounds__(256) void k_gemm_bt(const bf16* __restrict__ A,
                                                 const bf16* __restrict__ Bt,
                                                 float* __restrict__ Cf, bf16* __restrict__ Cb,
                                                 int M, int N, int K) {
  __shared__ __align__(16) bf16 sA[128 * 64];
  __shared__ __align__(16) bf16 sB[128 * 64];
  int nwg = gridDim.x * gridDim.y;
  int idl = blockIdx.y * gridDim.x + blockIdx.x;
  int cpx = nwg >> 3;
  int swz = (idl & 7) * cpx + (idl >> 3);
  int bx = swz % gridDim.x, by = swz / gridDim.x;
  int m0 = by * 128, n0 = bx * 128;
  int t = threadIdx.x, lane = t & 63, w = t >> 6;
  int wr = w >> 1, wc = w & 1;
  int lr = lane & 15, q2 = lane >> 4;
  int srow8 = lane >> 3, pc8 = lane & 7;
  f32x4 acc[4][4] = {};
  for (int k0 = 0; k0 < K; k0 += 64) {
#pragma unroll
    for (int is = 0; is < 4; is++) {
      int r = w * 32 + is * 8 + srow8;
      int lc = pc8 ^ (r & 7);
      G2L(A + (size_t)(m0 + r) * K + k0 + lc * 8, &sA[(w * 32 + is * 8) * 64]);
    }
#pragma unroll
    for (int is = 0; is < 4; is++) {
      int r = w * 32 + is * 8 + srow8;
      int lc = pc8 ^ (r & 7);
      G2L(Bt + (size_t)(n0 + r) * K + k0 + lc * 8, &sB[(w * 32 + is * 8) * 64]);
    }
    __syncthreads();
#pragma unroll
    for (int ch = 0; ch < 2; ch++) {
      bf16x8 af[4], bfr[4];
#pragma unroll
      for (int i = 0; i < 4; i++) {
        int r = wr * 64 + i * 16 + lr;
        af[i] = *(const bf16x8*)&sA[r * 64 + (((ch * 4 + q2) ^ (r & 7)) * 8)];
      }
#pragma unroll
      for (int i = 0; i < 4; i++) {
        int r = wc * 64 + i * 16 + lr;
        bfr[i] = *(const bf16x8*)&sB[r * 64 + (((ch * 4 + q2) ^ (r & 7)) * 8)];
      }
#pragma unroll
      for (int mi = 0; mi < 4; mi++)
#pragma unroll
        for (int ni = 0; ni < 4; ni++)
          acc[mi][ni] = __builtin_amdgcn_mfma_f32_16x16x32_bf16(af[mi], bfr[ni], acc[mi][ni], 0, 0, 0);
    }
    __syncthreads();
  }
  int row_base = m0 + wr * 64, col_base = n0 + wc * 64;
#pragma unroll
  for (int mi = 0; mi < 4; mi++)
#pragma unroll
    for (int ni = 0; ni < 4; ni++) {
      int col = col_base + ni * 16 + lr;
#pragma unroll
      for (int r = 0; r < 4; r++) {
        int row = row_base + mi * 16 + q2 * 4 + r;
        float v = acc[mi][ni][r];
        if (OUTF32) Cf[(size_t)row * N + col] = v;
        else        Cb[(size_t)row * N + col] = (bf16)v;
      }
    }
}

// ---------------- GEMM 64x128, 2-wave (proj) ----------------
__global__ __launch_bounds__(128) void k_gemm_64(const bf16* __restrict__ A,
                                                 const bf16* __restrict__ Bt,
                                                 float* __restrict__ Cf,
                                                 int M, int N, int K) {
  __shared__ __align__(16) bf16 sA[64 * 64];
  __shared__ __align__(16) bf16 sB[128 * 64];
  int nwg = gridDim.x * gridDim.y;
  int idl = blockIdx.y * gridDim.x + blockIdx.x;
  int cpx = nwg >> 3;
  int swz = (idl & 7) * cpx + (idl >> 3);
  int bx = swz % gridDim.x, by = swz / gridDim.x;
  int m0 = by * 64, n0 = bx * 128;
  int t = threadIdx.x, lane = t & 63, w = t >> 6;   // w in {0,1}
  int lr = lane & 15, q2 = lane >> 4;
  int srow8 = lane >> 3, pc8 = lane & 7;
  f32x4 acc[4][4] = {};
  for (int k0 = 0; k0 < K; k0 += 64) {
#pragma unroll
    for (int is = 0; is < 4; is++) {
      int r = w * 32 + is * 8 + srow8;
      int lc = pc8 ^ (r & 7);
      G2L(A + (size_t)(m0 + r) * K + k0 + lc * 8, &sA[(w * 32 + is * 8) * 64]);
    }
#pragma unroll
    for (int is = 0; is < 8; is++) {
      int r = w * 64 + is * 8 + srow8;
      int lc = pc8 ^ (r & 7);
      G2L(Bt + (size_t)(n0 + r) * K + k0 + lc * 8, &sB[(w * 64 + is * 8) * 64]);
    }
    __syncthreads();
#pragma unroll
    for (int ch = 0; ch < 2; ch++) {
      bf16x8 af[4], bfr[4];
#pragma unroll
      for (int i = 0; i < 4; i++) {
        int r = i * 16 + lr;
        af[i] = *(const bf16x8*)&sA[r * 64 + (((ch * 4 + q2) ^ (r & 7)) * 8)];
      }
#pragma unroll
      for (int i = 0; i < 4; i++) {
        int r = w * 64 + i * 16 + lr;
        bfr[i] = *(const bf16x8*)&sB[r * 64 + (((ch * 4 + q2) ^ (r & 7)) * 8)];
      }
#pragma unroll
      for (int mi = 0; mi < 4; mi++)
#pragma unroll
        for (int ni = 0; ni < 4; ni++)
          acc[mi][ni] = __builtin_amdgcn_mfma_f32_16x16x32_bf16(af[mi], bfr[ni], acc[mi][ni], 0, 0, 0);
    }
    __syncthreads();
  }
  int col_base = n0 + w * 64;
#pragma unroll
  for (int mi = 0; mi < 4; mi++)
#pragma unroll
    for (int ni = 0; ni < 4; ni++) {
      int col = col_base + ni * 16 + lr;
#pragma unroll
      for (int r = 0; r < 4; r++) {
        int row = m0 + mi * 16 + q2 * 4 + r;
        Cf[(size_t)row * N + col] = acc[mi][ni][r];
      }
    }
}

// ---------------- split-K causal flash: QBLK=128, 4 waves, chunk=6, longest-first ----------------
// 1632 blocks (51 slots x 32 bh), 256 threads, 16 KB LDS shared by 4 waves.
// Wave w owns q [qt*128 + w*32, +32). Direct attn write when whole row fits one chunk (qt<=2).
__global__ __launch_bounds__(256) void k_flash_part(const bf16* __restrict__ qr,
                                                    const bf16* __restrict__ kr,
                                                    const bf16* __restrict__ vt,
                                                    bf16* __restrict__ Opart,
                                                    float* __restrict__ ml,
                                                    bf16* __restrict__ attn) {
  const int T = 2048;
  int id = blockIdx.x;
  int slot = id >> 5;   // 0..50, slot 0 = longest (qt=15)
  int bh = id & 31;
  int qt = 15, c = 0;
  {
    int s = slot;
#pragma unroll 1
    for (int q = 15; q >= 0; --q) {
      int n = (2 * q + 7) / 6;    // ceil((2q+2)/6)
      if (s < n) { qt = q; c = s; break; }
      s -= n;
    }
  }
  int kt0 = c * 6;
  int nkt = 2 * qt + 2;
  int kt1 = nkt < kt0 + 6 ? nkt : kt0 + 6;   // exclusive

  __shared__ __align__(16) bf16 sK[64 * 64];
  __shared__ __align__(16) bf16 sV[64 * 64];
  int t = threadIdx.x, lane = t & 63, w = t >> 6;  // w in {0..3}
  int q31 = lane & 31, hi = lane >> 5;
  int srow8 = lane >> 3, pc8 = lane & 7;

  const bf16* Kbh = kr + (size_t)bh * T * 64;
  const bf16* Vbh = vt + (size_t)bh * 64 * T;

  int qwb = qt * 128 + w * 32;
  int qg = qwb + q31;
  const bf16* qrow = qr + ((size_t)bh * T + qg) * 64 + hi * 8;
  bf16x8 qf[4];
#pragma unroll
  for (int ks = 0; ks < 4; ks++) qf[ks] = *(const bf16x8*)(qrow + ks * 16);
  f32x16 o0 = {}, o1 = {};
  float m = -1e30f, l = 0.f;

  // 4 waves split the 64-row K and V tiles: wave w stages rows [w*16, w*16+16)
  auto stage = [&](int kt) {
#pragma unroll
    for (int is = 0; is < 2; is++) {
      int r = w * 16 + is * 8 + srow8;
      int lc = pc8 ^ (r & 7);
      G2L(Kbh + (size_t)(kt * 64 + r) * 64 + lc * 8, &sK[(w * 16 + is * 8) * 64]);
    }
#pragma unroll
    for (int is = 0; is < 2; is++) {
      int d = w * 16 + is * 8 + srow8;
      int lc = pc8 ^ (d & 7);
      G2L(Vbh + (size_t)d * T + kt * 64 + lc * 8, &sV[(w * 16 + is * 8) * 64]);
    }
  };

  stage(kt0);
  for (int kt = kt0; kt < kt1; kt++) {
    asm volatile("s_waitcnt vmcnt(0)" ::: "memory");
    __builtin_amdgcn_s_barrier();
    asm volatile("" ::: "memory");
    __builtin_amdgcn_sched_barrier(0);
    // ---- S^T = K Q^T (log2 domain) ----
    f32x16 s[2];
    __builtin_amdgcn_s_setprio(1);
#pragma unroll
    for (int kb = 0; kb < 2; kb++) {
      f32x16 a = {};
      int krow = kb * 32 + q31;
#pragma unroll
      for (int ks = 0; ks < 4; ks++) {
        int ch = (ks * 2 + hi) ^ (krow & 7);
        bf16x8 kf = *(const bf16x8*)&sK[krow * 64 + ch * 8];
        a = __builtin_amdgcn_mfma_f32_32x32x16_bf16(kf, qf[ks], a, 0, 0, 0);
      }
      s[kb] = a;
    }
    __builtin_amdgcn_s_setprio(0);
    if (kt >= 2 * qt) {  // last two k-tiles overlap the q range: per-lane causal mask
      int thr = qg - kt * 64;
#pragma unroll
      for (int kb = 0; kb < 2; kb++)
#pragma unroll
        for (int r = 0; r < 16; r++) {
          int koff = kb * 32 + (r & 3) + 8 * (r >> 2) + 4 * hi;
          if (koff > thr) s[kb][r] = -1e30f;
        }
    }
    // ---- softmax: max via v_max3 tree ----
    float tm[16];
#pragma unroll
    for (int i = 0; i < 16; i++) tm[i] = fmaxf(s[0][i], s[1][i]);
    float a0 = m3(tm[0], tm[1], tm[2]);
    float a1 = m3(tm[3], tm[4], tm[5]);
    float a2 = m3(tm[6], tm[7], tm[8]);
    float a3 = m3(tm[9], tm[10], tm[11]);
    float a4 = m3(tm[12], tm[13], tm[14]);
    float b0 = m3(a0, a1, tm[15]);
    float b1 = m3(a2, a3, a4);
    float px = fmaxf(b0, b1);
    px = fmaxf(px, __shfl_xor(px, 32, 64));
    float mn = fmaxf(m, px);
    float alpha = fexp2(m - mn);
    m = mn;
    float ts[16];
#pragma unroll
    for (int i = 0; i < 16; i++) {
      float p0 = fexp2(s[0][i] - m);
      float p1 = fexp2(s[1][i] - m);
      s[0][i] = p0;
      s[1][i] = p1;
      ts[i] = p0 + p1;
    }
#pragma unroll
    for (int st = 8; st > 0; st >>= 1)
#pragma unroll
      for (int i = 0; i < st; i++) ts[i] += ts[i + st];
    float rs = ts[0];
    rs += __shfl_xor(rs, 32, 64);
    l = l * alpha + rs;
    // ---- P -> PV B-frags (cvt_pk + permlane32_swap) ----
    int pw[4][4];
#pragma unroll
    for (int kb = 0; kb < 2; kb++) {
      int wd[8];
#pragma unroll
      for (int g = 0; g < 4; g++) {
        bf16x2 a, cc;
        a[0] = (bf16)s[kb][4 * g + 0]; a[1] = (bf16)s[kb][4 * g + 1];
        cc[0] = (bf16)s[kb][4 * g + 2]; cc[1] = (bf16)s[kb][4 * g + 3];
        wd[2 * g]     = __builtin_bit_cast(int, a);
        wd[2 * g + 1] = __builtin_bit_cast(int, cc);
      }
      asm volatile("v_permlane32_swap_b32 %0, %1" : "+v"(wd[0]), "+v"(wd[2]));
      asm volatile("v_permlane32_swap_b32 %0, %1" : "+v"(wd[1]), "+v"(wd[3]));
      asm volatile("v_permlane32_swap_b32 %0, %1" : "+v"(wd[4]), "+v"(wd[6]));
      asm volatile("v_permlane32_swap_b32 %0, %1" : "+v"(wd[5]), "+v"(wd[7]));
      pw[2 * kb][0] = wd[0]; pw[2 * kb][1] = wd[1];
      pw[2 * kb][2] = wd[2]; pw[2 * kb][3] = wd[3];
      pw[2 * kb + 1][0] = wd[4]; pw[2 * kb + 1][1] = wd[5];
      pw[2 * kb + 1][2] = wd[6]; pw[2 * kb + 1][3] = wd[7];
    }
    // ---- rescale O ----
#pragma unroll
    for (int r = 0; r < 16; r++) { o0[r] *= alpha; o1[r] *= alpha; }
    // ---- O^T += V^T P^T ----
    __builtin_amdgcn_s_setprio(1);
#pragma unroll
    for (int ks = 0; ks < 4; ks++) {
      i32x4 pv = {pw[ks][0], pw[ks][1], pw[ks][2], pw[ks][3]};
      bf16x8 pb = __builtin_bit_cast(bf16x8, pv);
      {
        int drow = q31;
        int ch = (ks * 2 + hi) ^ (drow & 7);
        bf16x8 vf = *(const bf16x8*)&sV[drow * 64 + ch * 8];
        o0 = __builtin_amdgcn_mfma_f32_32x32x16_bf16(vf, pb, o0, 0, 0, 0);
      }
      {
        int drow = 32 + q31;
        int ch = (ks * 2 + hi) ^ (drow & 7);
        bf16x8 vf = *(const bf16x8*)&sV[drow * 64 + ch * 8];
        o1 = __builtin_amdgcn_mfma_f32_32x32x16_bf16(vf, pb, o1, 0, 0, 0);
      }
    }
    __builtin_amdgcn_s_setprio(0);
    asm volatile("" ::: "memory");
    __builtin_amdgcn_s_barrier();   // all waves done reading before next stage overwrites
    asm volatile("" ::: "memory");
    if (kt + 1 < kt1) stage(kt + 1);
  }
  if (kt0 == 0 && kt1 == nkt) {
    // whole causal row in one chunk (qt<=2): normalize and write attn directly
    int b = bh >> 4, h = bh & 15;
    float linv = 1.0f / l;
    bf16* orow = attn + ((size_t)b * T + qg) * 1024 + h * 64;
#pragma unroll
    for (int g = 0; g < 4; g++) {
      bf16x4 v0, v1;
#pragma unroll
      for (int j = 0; j < 4; j++) {
        v0[j] = (bf16)(o0[4 * g + j] * linv);
        v1[j] = (bf16)(o1[4 * g + j] * linv);
      }
      *(bf16x4*)&orow[8 * g + 4 * hi]      = v0;
      *(bf16x4*)&orow[32 + 8 * g + 4 * hi] = v1;
    }
  } else {
    int qloc = w * 32 + q31;   // 0..127
    bf16* Ob = Opart + (size_t)id * 8192 + qloc * 64;
#pragma unroll
    for (int g = 0; g < 4; g++) {
      bf16x4 v0, v1;
#pragma unroll
      for (int j = 0; j < 4; j++) {
        v0[j] = (bf16)o0[4 * g + j];
        v1[j] = (bf16)o1[4 * g + j];
      }
      *(bf16x4*)&Ob[8 * g + 4 * hi]      = v0;
      *(bf16x4*)&Ob[32 + 8 * g + 4 * hi] = v1;
    }
    if (hi == 0) {
      ml[(size_t)id * 256 + qloc]       = m;
      ml[(size_t)id * 256 + 128 + qloc] = l;
    }
  }
}

// ---------------- combine partials (qt64 >= 6 only) -> attn ----------------
__global__ __launch_bounds__(256) void k_combine(const bf16* __restrict__ Opart,
                                                 const float* __restrict__ ml,
                                                 bf16* __restrict__ attn) {
  int bhqt = blockIdx.x;          // 832 = 26 qt64 x 32 bh
  int bh = bhqt & 31, qt64 = 6 + (bhqt >> 5);
  int qt = qt64 >> 1, qh = qt64 & 1;   // 128-q block index, half
  int b = bh >> 4, h = bh & 15;
  int nch = (2 * qt + 7) / 6;
  int slot0 = 0;
#pragma unroll 1
  for (int q = 15; q > qt; --q) slot0 += (2 * q + 7) / 6;
  int t = threadIdx.x;
  int q = t >> 2, ds = (t & 3) * 16;
  int qloc = qh * 64 + q;
  float M = -1e30f;
  for (int c = 0; c < nch; c++)
    M = fmaxf(M, ml[(size_t)((slot0 + c) * 32 + bh) * 256 + qloc]);
  float acc[16] = {};
  float L = 0.f;
  for (int c = 0; c < nch; c++) {
    int p = (slot0 + c) * 32 + bh;
    float wgt = fexp2(ml[(size_t)p * 256 + qloc] - M);
    L += wgt * ml[(size_t)p * 256 + 128 + qloc];
    const bf16* row = Opart + (size_t)p * 8192 + qloc * 64 + ds;
    bf16x8 a0 = *(const bf16x8*)row;
    bf16x8 a1 = *(const bf16x8*)(row + 8);
#pragma unroll
    for (int i = 0; i < 8; i++) {
      acc[i]     += wgt * (float)a0[i];
      acc[i + 8] += wgt * (float)a1[i];
    }
  }
  float Linv = 1.0f / L;
  bf16x8 w0, w1;
#pragma unroll
  for (int i = 0; i < 8; i++) {
    w0[i] = (bf16)(acc[i] * Linv);
    w1[i] = (bf16)(acc[i + 8] * Linv);
  }
  bf16* dst = attn + ((size_t)(b * 2048) + qt64 * 64 + q) * 1024 + h * 64 + ds;
  *(bf16x8*)dst = w0;
  *(bf16x8*)(dst + 8) = w1;
}

// ---------------- launch ----------------
extern "C" void kernel_launch(void* const* d_in, const int* in_sizes, int n_in,
                              void* d_out, int out_size, void* d_ws, size_t ws_size,
                              hipStream_t stream) {
  const float* x     = (const float*)d_in[0];
  const float* Wqkv  = (const float*)d_in[1];
  const float* Wproj = (const float*)d_in[2];
  float* outp = (float*)d_out;
  const int B = 2, T = 2048, C = 1024;
  const int M = B * T;  // 4096

  char* ws = (char*)d_ws;
  size_t off = 0;
  auto alloc = [&](size_t bytes) {
    void* p = ws + off;
    off += (bytes + 255) & ~(size_t)255;
    return p;
  };
  bf16* xb     = (bf16*)alloc((size_t)M * C * 2);        // 8 MB; attn aliases after gemm
  bf16* wprojt = (bf16*)alloc((size_t)C * C * 2);        // 2 MB
  float* cosT  = (float*)alloc((size_t)T * 32 * 4);
  float* sinT  = (float*)alloc((size_t)T * 32 * 4);
  bf16* region = (bf16*)alloc((size_t)M * 3 * C * 2 + (size_t)3 * C * C * 2);  // 30 MB: qkv + wqkvt
  bf16* qkv    = region;                                 // 24 MB; dead after rope_v
  bf16* wqkvt  = region + (size_t)M * 3 * C;             // 6 MB; dead after qkv gemm
  bf16* qr     = (bf16*)alloc((size_t)M * C * 2);
  bf16* kr     = (bf16*)alloc((size_t)M * C * 2);
  bf16* vt     = (bf16*)alloc((size_t)M * C * 2);
  // aliases (lifetimes disjoint, stream-ordered):
  bf16* attn   = xb;                                     // xb dead after qkv gemm
  bf16* Opart  = region;                                 // 1632*8192*2 = 26.75 MB
  float* ml    = (float*)(region + (size_t)1632 * 8192); // 1.67 MB -> region ends at 28.4 MB

  k_prep<<<dim3(6400), dim3(256), 0, stream>>>(x, xb, cosT, sinT, Wqkv, wqkvt, Wproj, wprojt);
  k_gemm_bt<0><<<dim3(3 * C / 128, M / 128), dim3(256), 0, stream>>>(xb, wqkvt, (float*)nullptr, qkv, M, 3 * C, C);
  k_rope_v<<<dim3(T / 64, 32), dim3(256), 0, stream>>>(qkv, cosT, sinT, qr, kr, vt);
  k_flash_part<<<dim3(1632), dim3(256), 0, stream>>>(qr, kr, vt, Opart, ml, attn);
  k_combine<<<dim3(832), dim3(256), 0, stream>>>(Opart, ml, attn);
  k_gemm_64<<<dim3(C / 128, M / 64), dim3(128), 0, stream>>>(attn, wprojt, outp, M, C, C);
}

// Round 19
// 122.060 us; speedup vs baseline: 1.0259x; 1.0259x over previous
//
#include <hip/hip_runtime.h>
#include <cstdint>
#include <cstddef>

typedef __bf16 bf16;
typedef __bf16 bf16x2 __attribute__((ext_vector_type(2)));
typedef __bf16 bf16x4 __attribute__((ext_vector_type(4)));
typedef __bf16 bf16x8 __attribute__((ext_vector_type(8)));
typedef float  f32x4  __attribute__((ext_vector_type(4)));
typedef float  f32x16 __attribute__((ext_vector_type(16)));
typedef int    i32x4  __attribute__((ext_vector_type(4)));

// raw 2^x (v_exp_f32, TRANS pipe, 1 instruction)
__device__ __forceinline__ float fexp2(float x) {
  float r;
  asm("v_exp_f32 %0, %1" : "=v"(r) : "v"(x));
  return r;
}
__device__ __forceinline__ float m3(float a, float b, float c) {
  return fmaxf(fmaxf(a, b), c);   // clang fuses to v_max3_f32
}

// global -> LDS direct (16B/lane, dest = wave-uniform base + lane*16)
#define G2L(src, dst)                                                          \
  __builtin_amdgcn_global_load_lds(                                            \
      (const __attribute__((address_space(1))) unsigned int*)(src),            \
      (__attribute__((address_space(3))) unsigned int*)(dst), 16, 0, 0)

// ---------------- fused prep: x convert (0..2047) + rope tables (2048..2303)
//                  + weight transposes (2304..6399) ----------------
__global__ void k_prep(const float* __restrict__ x, bf16* __restrict__ xb,
                       float* __restrict__ cosT, float* __restrict__ sinT,
                       const float* __restrict__ wqkv, bf16* __restrict__ wqkvt,
                       const float* __restrict__ wproj, bf16* __restrict__ wprojt) {
  __shared__ float tile[32][33];
  int bx = blockIdx.x;
  if (bx < 2048) {
    int i = (bx * 256 + threadIdx.x) * 8;
    float4 a = *(const float4*)(x + i);
    float4 b = *(const float4*)(x + i + 4);
    bf16x8 o;
    o[0] = (bf16)a.x; o[1] = (bf16)a.y; o[2] = (bf16)a.z; o[3] = (bf16)a.w;
    o[4] = (bf16)b.x; o[5] = (bf16)b.y; o[6] = (bf16)b.z; o[7] = (bf16)b.w;
    *(bf16x8*)(xb + i) = o;
  } else if (bx < 2304) {
    int i = (bx - 2048) * 256 + threadIdx.x;   // 0..65535
    int t = i >> 5, j = i & 31;
    float inv = powf(10000.0f, -(float)j * (1.0f / 32.0f));
    float f = (float)t * inv;
    cosT[i] = cosf(f);
    sinT[i] = sinf(f);
  } else {
    int tb = bx - 2304;              // 0..4095
    int ty = tb >> 7, tx = tb & 127;
    const float* in;
    bf16* out;
    int C;
    if (tx < 96) { in = wqkv; out = wqkvt; C = 3072; }
    else         { in = wproj; out = wprojt; C = 1024; tx -= 96; }
    const int R = 1024;
    int c0 = tx * 32, r0 = ty * 32;
    int lx = threadIdx.x & 31, ly = threadIdx.x >> 5;  // 32 x 8
#pragma unroll
    for (int i = 0; i < 32; i += 8)
      tile[ly + i][lx] = in[(size_t)(r0 + ly + i) * C + c0 + lx];
    __syncthreads();
#pragma unroll
    for (int i = 0; i < 32; i += 8)
      out[(size_t)(c0 + ly + i) * R + r0 + lx] = (bf16)tile[lx][ly + i];
  }
}

// ---------------- fused RoPE(q,k) + V-transpose: one pass over qkv ----------------
__global__ __launch_bounds__(256) void k_rope_v(const bf16* __restrict__ qkv,
                                                const float* __restrict__ cosT,
                                                const float* __restrict__ sinT,
                                                bf16* __restrict__ qr,
                                                bf16* __restrict__ kr,
                                                bf16* __restrict__ vt) {
  __shared__ bf16 tile[64][66];
  int bh = blockIdx.y;           // 0..31
  int t0 = blockIdx.x * 64;
  int b = bh >> 4, h = bh & 15;
  int tt = threadIdx.x >> 2, g = threadIdx.x & 3;
  int c4 = g * 16;
  const bf16* row = qkv + (size_t)(b * 2048 + t0 + tt) * 3072 + h * 64;
  bf16x8 v0 = *(const bf16x8*)(row + 2048 + c4);
  bf16x8 v1 = *(const bf16x8*)(row + 2048 + c4 + 8);
#pragma unroll
  for (int j = 0; j < 8; j++) { tile[tt][c4 + j] = v0[j]; tile[tt][c4 + 8 + j] = v1[j]; }
  int tglob = t0 + tt;
  size_t ob = ((size_t)bh * 2048 + tglob) * 64;
  const float QS = 0.125f * 1.44269504f;
  bf16x8 qlo = *(const bf16x8*)(row + g * 8);
  bf16x8 qhi = *(const bf16x8*)(row + 32 + g * 8);
  bf16x8 klo = *(const bf16x8*)(row + 1024 + g * 8);
  bf16x8 khi = *(const bf16x8*)(row + 1024 + 32 + g * 8);
  bf16x8 qo0, qo1, ko0, ko1;
#pragma unroll
  for (int j = 0; j < 8; j++) {
    float c = cosT[tglob * 32 + g * 8 + j], s = sinT[tglob * 32 + g * 8 + j];
    float ql = (float)qlo[j], qh = (float)qhi[j];
    float kl = (float)klo[j], kh = (float)khi[j];
    qo0[j] = (bf16)((ql * c - qh * s) * QS);
    qo1[j] = (bf16)((qh * c + ql * s) * QS);
    ko0[j] = (bf16)(kl * c - kh * s);
    ko1[j] = (bf16)(kh * c + kl * s);
  }
  *(bf16x8*)&qr[ob + g * 8]      = qo0;
  *(bf16x8*)&qr[ob + 32 + g * 8] = qo1;
  *(bf16x8*)&kr[ob + g * 8]      = ko0;
  *(bf16x8*)&kr[ob + 32 + g * 8] = ko1;
  __syncthreads();
  int d = threadIdx.x >> 2, tc0 = (threadIdx.x & 3) * 16;
  bf16x8 o0, o1;
#pragma unroll
  for (int j = 0; j < 8; j++) { o0[j] = tile[tc0 + j][d]; o1[j] = tile[tc0 + 8 + j][d]; }
  bf16* dst = vt + ((size_t)bh * 64 + d) * 2048 + t0 + tc0;
  *(bf16x8*)dst = o0;
  *(bf16x8*)(dst + 8) = o1;
}

// ---------------- GEMM 128x128 (m97 structure + XCD swizzle): C = A * Bt^T ----------------
template <int OUTF32>
__global__ __launch_bounds__(256) void k_gemm_bt(const bf16* __restrict__ A,
                                                 const bf16* __restrict__ Bt,
                                                 float* __restrict__ Cf, bf16* __restrict__ Cb,
                                                 int M, int N, int K) {
  __shared__ __align__(16) bf16 sA[128 * 64];
  __shared__ __align__(16) bf16 sB[128 * 64];
  int nwg = gridDim.x * gridDim.y;
  int idl = blockIdx.y * gridDim.x + blockIdx.x;
  int cpx = nwg >> 3;
  int swz = (idl & 7) * cpx + (idl >> 3);
  int bx = swz % gridDim.x, by = swz / gridDim.x;
  int m0 = by * 128, n0 = bx * 128;
  int t = threadIdx.x, lane = t & 63, w = t >> 6;
  int wr = w >> 1, wc = w & 1;
  int lr = lane & 15, q2 = lane >> 4;
  int srow8 = lane >> 3, pc8 = lane & 7;
  f32x4 acc[4][4] = {};
  for (int k0 = 0; k0 < K; k0 += 64) {
#pragma unroll
    for (int is = 0; is < 4; is++) {
      int r = w * 32 + is * 8 + srow8;
      int lc = pc8 ^ (r & 7);
      G2L(A + (size_t)(m0 + r) * K + k0 + lc * 8, &sA[(w * 32 + is * 8) * 64]);
    }
#pragma unroll
    for (int is = 0; is < 4; is++) {
      int r = w * 32 + is * 8 + srow8;
      int lc = pc8 ^ (r & 7);
      G2L(Bt + (size_t)(n0 + r) * K + k0 + lc * 8, &sB[(w * 32 + is * 8) * 64]);
    }
    __syncthreads();
#pragma unroll
    for (int ch = 0; ch < 2; ch++) {
      bf16x8 af[4], bfr[4];
#pragma unroll
      for (int i = 0; i < 4; i++) {
        int r = wr * 64 + i * 16 + lr;
        af[i] = *(const bf16x8*)&sA[r * 64 + (((ch * 4 + q2) ^ (r & 7)) * 8)];
      }
#pragma unroll
      for (int i = 0; i < 4; i++) {
        int r = wc * 64 + i * 16 + lr;
        bfr[i] = *(const bf16x8*)&sB[r * 64 + (((ch * 4 + q2) ^ (r & 7)) * 8)];
      }
#pragma unroll
      for (int mi = 0; mi < 4; mi++)
#pragma unroll
        for (int ni = 0; ni < 4; ni++)
          acc[mi][ni] = __builtin_amdgcn_mfma_f32_16x16x32_bf16(af[mi], bfr[ni], acc[mi][ni], 0, 0, 0);
    }
    __syncthreads();
  }
  int row_base = m0 + wr * 64, col_base = n0 + wc * 64;
#pragma unroll
  for (int mi = 0; mi < 4; mi++)
#pragma unroll
    for (int ni = 0; ni < 4; ni++) {
      int col = col_base + ni * 16 + lr;
#pragma unroll
      for (int r = 0; r < 4; r++) {
        int row = row_base + mi * 16 + q2 * 4 + r;
        float v = acc[mi][ni][r];
        if (OUTF32) Cf[(size_t)row * N + col] = v;
        else        Cb[(size_t)row * N + col] = (bf16)v;
      }
    }
}

// ---------------- GEMM 64x128, 2-wave (proj) ----------------
__global__ __launch_bounds__(128) void k_gemm_64(const bf16* __restrict__ A,
                                                 const bf16* __restrict__ Bt,
                                                 float* __restrict__ Cf,
                                                 int M, int N, int K) {
  __shared__ __align__(16) bf16 sA[64 * 64];
  __shared__ __align__(16) bf16 sB[128 * 64];
  int nwg = gridDim.x * gridDim.y;
  int idl = blockIdx.y * gridDim.x + blockIdx.x;
  int cpx = nwg >> 3;
  int swz = (idl & 7) * cpx + (idl >> 3);
  int bx = swz % gridDim.x, by = swz / gridDim.x;
  int m0 = by * 64, n0 = bx * 128;
  int t = threadIdx.x, lane = t & 63, w = t >> 6;   // w in {0,1}
  int lr = lane & 15, q2 = lane >> 4;
  int srow8 = lane >> 3, pc8 = lane & 7;
  f32x4 acc[4][4] = {};
  for (int k0 = 0; k0 < K; k0 += 64) {
#pragma unroll
    for (int is = 0; is < 4; is++) {
      int r = w * 32 + is * 8 + srow8;
      int lc = pc8 ^ (r & 7);
      G2L(A + (size_t)(m0 + r) * K + k0 + lc * 8, &sA[(w * 32 + is * 8) * 64]);
    }
#pragma unroll
    for (int is = 0; is < 8; is++) {
      int r = w * 64 + is * 8 + srow8;
      int lc = pc8 ^ (r & 7);
      G2L(Bt + (size_t)(n0 + r) * K + k0 + lc * 8, &sB[(w * 64 + is * 8) * 64]);
    }
    __syncthreads();
#pragma unroll
    for (int ch = 0; ch < 2; ch++) {
      bf16x8 af[4], bfr[4];
#pragma unroll
      for (int i = 0; i < 4; i++) {
        int r = i * 16 + lr;
        af[i] = *(const bf16x8*)&sA[r * 64 + (((ch * 4 + q2) ^ (r & 7)) * 8)];
      }
#pragma unroll
      for (int i = 0; i < 4; i++) {
        int r = w * 64 + i * 16 + lr;
        bfr[i] = *(const bf16x8*)&sB[r * 64 + (((ch * 4 + q2) ^ (r & 7)) * 8)];
      }
#pragma unroll
      for (int mi = 0; mi < 4; mi++)
#pragma unroll
        for (int ni = 0; ni < 4; ni++)
          acc[mi][ni] = __builtin_amdgcn_mfma_f32_16x16x32_bf16(af[mi], bfr[ni], acc[mi][ni], 0, 0, 0);
    }
    __syncthreads();
  }
  int col_base = n0 + w * 64;
#pragma unroll
  for (int mi = 0; mi < 4; mi++)
#pragma unroll
    for (int ni = 0; ni < 4; ni++) {
      int col = col_base + ni * 16 + lr;
#pragma unroll
      for (int r = 0; r < 4; r++) {
        int row = m0 + mi * 16 + q2 * 4 + r;
        Cf[(size_t)row * N + col] = acc[mi][ni][r];
      }
    }
}

// ---------------- split-K causal flash (R12 config) + direct write for qt<=5 ----------------
__global__ __launch_bounds__(128) void k_flash_part(const bf16* __restrict__ qr,
                                                    const bf16* __restrict__ kr,
                                                    const bf16* __restrict__ vt,
                                                    bf16* __restrict__ Opart,
                                                    float* __restrict__ ml,
                                                    bf16* __restrict__ attn) {
  const int T = 2048;
  int id = blockIdx.x;
  int slot = id >> 5;   // 0..101, slot 0 = longest (qt=31)
  int bh = id & 31;
  int qt = 31, c = 0;
  {
    int s = slot;
#pragma unroll 1
    for (int q = 31; q >= 0; --q) {
      int n = q / 6 + 1;
      if (s < n) { qt = q; c = s; break; }
      s -= n;
    }
  }
  int kt0 = c * 6;
  int kt1 = qt + 1 < kt0 + 6 ? qt + 1 : kt0 + 6;   // exclusive

  __shared__ __align__(16) bf16 sK[64 * 64];
  __shared__ __align__(16) bf16 sV[64 * 64];
  int t = threadIdx.x, lane = t & 63, w = t >> 6;  // w in {0,1}
  int q31 = lane & 31, hi = lane >> 5;
  int srow8 = lane >> 3, pc8 = lane & 7;

  const bf16* Kbh = kr + (size_t)bh * T * 64;
  const bf16* Vbh = vt + (size_t)bh * 64 * T;

  int qwb = qt * 64 + w * 32;
  int qg = qwb + q31;
  const bf16* qrow = qr + ((size_t)bh * T + qg) * 64 + hi * 8;
  bf16x8 qf[4];
#pragma unroll
  for (int ks = 0; ks < 4; ks++) qf[ks] = *(const bf16x8*)(qrow + ks * 16);
  f32x16 o0 = {}, o1 = {};
  float m = -1e30f, l = 0.f;

  auto stage = [&](int kt) {
#pragma unroll
    for (int is = 0; is < 4; is++) {
      int r = w * 32 + is * 8 + srow8;
      int lc = pc8 ^ (r & 7);
      G2L(Kbh + (size_t)(kt * 64 + r) * 64 + lc * 8, &sK[(w * 32 + is * 8) * 64]);
    }
#pragma unroll
    for (int is = 0; is < 4; is++) {
      int d = w * 32 + is * 8 + srow8;
      int lc = pc8 ^ (d & 7);
      G2L(Vbh + (size_t)d * T + kt * 64 + lc * 8, &sV[(w * 32 + is * 8) * 64]);
    }
  };

  stage(kt0);
  for (int kt = kt0; kt < kt1; kt++) {
    asm volatile("s_waitcnt vmcnt(0)" ::: "memory");
    __builtin_amdgcn_s_barrier();
    asm volatile("" ::: "memory");
    __builtin_amdgcn_sched_barrier(0);
    // ---- S^T = K Q^T (log2 domain) ----
    f32x16 s[2];
    __builtin_amdgcn_s_setprio(1);
#pragma unroll
    for (int kb = 0; kb < 2; kb++) {
      f32x16 a = {};
      int krow = kb * 32 + q31;
#pragma unroll
      for (int ks = 0; ks < 4; ks++) {
        int ch = (ks * 2 + hi) ^ (krow & 7);
        bf16x8 kf = *(const bf16x8*)&sK[krow * 64 + ch * 8];
        a = __builtin_amdgcn_mfma_f32_32x32x16_bf16(kf, qf[ks], a, 0, 0, 0);
      }
      s[kb] = a;
    }
    __builtin_amdgcn_s_setprio(0);
    if (kt == qt) {  // diagonal mask
      int thr = qg - kt * 64;
#pragma unroll
      for (int kb = 0; kb < 2; kb++)
#pragma unroll
        for (int r = 0; r < 16; r++) {
          int koff = kb * 32 + (r & 3) + 8 * (r >> 2) + 4 * hi;
          if (koff > thr) s[kb][r] = -1e30f;
        }
    }
    // ---- softmax: max via v_max3 tree ----
    float tm[16];
#pragma unroll
    for (int i = 0; i < 16; i++) tm[i] = fmaxf(s[0][i], s[1][i]);
    float a0 = m3(tm[0], tm[1], tm[2]);
    float a1 = m3(tm[3], tm[4], tm[5]);
    float a2 = m3(tm[6], tm[7], tm[8]);
    float a3 = m3(tm[9], tm[10], tm[11]);
    float a4 = m3(tm[12], tm[13], tm[14]);
    float b0 = m3(a0, a1, tm[15]);
    float b1 = m3(a2, a3, a4);
    float px = fmaxf(b0, b1);
    px = fmaxf(px, __shfl_xor(px, 32, 64));
    float mn = fmaxf(m, px);
    float alpha = fexp2(m - mn);
    m = mn;
    float ts[16];
#pragma unroll
    for (int i = 0; i < 16; i++) {
      float p0 = fexp2(s[0][i] - m);
      float p1 = fexp2(s[1][i] - m);
      s[0][i] = p0;
      s[1][i] = p1;
      ts[i] = p0 + p1;
    }
#pragma unroll
    for (int st = 8; st > 0; st >>= 1)
#pragma unroll
      for (int i = 0; i < st; i++) ts[i] += ts[i + st];
    float rs = ts[0];
    rs += __shfl_xor(rs, 32, 64);
    l = l * alpha + rs;
    // ---- P -> PV B-frags (cvt_pk + permlane32_swap) ----
    int pw[4][4];
#pragma unroll
    for (int kb = 0; kb < 2; kb++) {
      int wd[8];
#pragma unroll
      for (int g = 0; g < 4; g++) {
        bf16x2 a, cc;
        a[0] = (bf16)s[kb][4 * g + 0]; a[1] = (bf16)s[kb][4 * g + 1];
        cc[0] = (bf16)s[kb][4 * g + 2]; cc[1] = (bf16)s[kb][4 * g + 3];
        wd[2 * g]     = __builtin_bit_cast(int, a);
        wd[2 * g + 1] = __builtin_bit_cast(int, cc);
      }
      asm volatile("v_permlane32_swap_b32 %0, %1" : "+v"(wd[0]), "+v"(wd[2]));
      asm volatile("v_permlane32_swap_b32 %0, %1" : "+v"(wd[1]), "+v"(wd[3]));
      asm volatile("v_permlane32_swap_b32 %0, %1" : "+v"(wd[4]), "+v"(wd[6]));
      asm volatile("v_permlane32_swap_b32 %0, %1" : "+v"(wd[5]), "+v"(wd[7]));
      pw[2 * kb][0] = wd[0]; pw[2 * kb][1] = wd[1];
      pw[2 * kb][2] = wd[2]; pw[2 * kb][3] = wd[3];
      pw[2 * kb + 1][0] = wd[4]; pw[2 * kb + 1][1] = wd[5];
      pw[2 * kb + 1][2] = wd[6]; pw[2 * kb + 1][3] = wd[7];
    }
    // ---- rescale O ----
#pragma unroll
    for (int r = 0; r < 16; r++) { o0[r] *= alpha; o1[r] *= alpha; }
    // ---- O^T += V^T P^T ----
    __builtin_amdgcn_s_setprio(1);
#pragma unroll
    for (int ks = 0; ks < 4; ks++) {
      i32x4 pv = {pw[ks][0], pw[ks][1], pw[ks][2], pw[ks][3]};
      bf16x8 pb = __builtin_bit_cast(bf16x8, pv);
      {
        int drow = q31;
        int ch = (ks * 2 + hi) ^ (drow & 7);
        bf16x8 vf = *(const bf16x8*)&sV[drow * 64 + ch * 8];
        o0 = __builtin_amdgcn_mfma_f32_32x32x16_bf16(vf, pb, o0, 0, 0, 0);
      }
      {
        int drow = 32 + q31;
        int ch = (ks * 2 + hi) ^ (drow & 7);
        bf16x8 vf = *(const bf16x8*)&sV[drow * 64 + ch * 8];
        o1 = __builtin_amdgcn_mfma_f32_32x32x16_bf16(vf, pb, o1, 0, 0, 0);
      }
    }
    __builtin_amdgcn_s_setprio(0);
    asm volatile("" ::: "memory");
    __builtin_amdgcn_s_barrier();   // all waves done reading before next stage overwrites
    asm volatile("" ::: "memory");
    if (kt + 1 < kt1) stage(kt + 1);
  }
  if (kt0 == 0 && kt1 == qt + 1) {
    // single-chunk row (qt<=5): normalize and write attn directly
    int b = bh >> 4, h = bh & 15;
    float linv = 1.0f / l;
    bf16* orow = attn + ((size_t)b * T + qg) * 1024 + h * 64;
#pragma unroll
    for (int g = 0; g < 4; g++) {
      bf16x4 v0, v1;
#pragma unroll
      for (int j = 0; j < 4; j++) {
        v0[j] = (bf16)(o0[4 * g + j] * linv);
        v1[j] = (bf16)(o1[4 * g + j] * linv);
      }
      *(bf16x4*)&orow[8 * g + 4 * hi]      = v0;
      *(bf16x4*)&orow[32 + 8 * g + 4 * hi] = v1;
    }
  } else {
    int qloc = w * 32 + q31;
    bf16* Ob = Opart + (size_t)id * 4096 + qloc * 64;
#pragma unroll
    for (int g = 0; g < 4; g++) {
      bf16x4 v0, v1;
#pragma unroll
      for (int j = 0; j < 4; j++) {
        v0[j] = (bf16)o0[4 * g + j];
        v1[j] = (bf16)o1[4 * g + j];
      }
      *(bf16x4*)&Ob[8 * g + 4 * hi]      = v0;
      *(bf16x4*)&Ob[32 + 8 * g + 4 * hi] = v1;
    }
    if (hi == 0) {
      ml[(size_t)id * 128 + qloc]      = m;
      ml[(size_t)id * 128 + 64 + qloc] = l;
    }
  }
}

// ---------------- combine partials (qt >= 6 only) -> attn ----------------
__global__ __launch_bounds__(256) void k_combine(const bf16* __restrict__ Opart,
                                                 const float* __restrict__ ml,
                                                 bf16* __restrict__ attn) {
  int bhqt = blockIdx.x;          // 832 = 26 qt x 32 bh
  int bh = bhqt & 31, qt = 6 + (bhqt >> 5);
  int b = bh >> 4, h = bh & 15;
  int nch = qt / 6 + 1;
  int slot0 = 0;
#pragma unroll 1
  for (int q = 31; q > qt; --q) slot0 += q / 6 + 1;
  int t = threadIdx.x;
  int q = t >> 2, ds = (t & 3) * 16;
  float M = -1e30f;
  for (int c = 0; c < nch; c++)
    M = fmaxf(M, ml[(size_t)((slot0 + c) * 32 + bh) * 128 + q]);
  float acc[16] = {};
  float L = 0.f;
  for (int c = 0; c < nch; c++) {
    int p = (slot0 + c) * 32 + bh;
    float wgt = fexp2(ml[(size_t)p * 128 + q] - M);
    L += wgt * ml[(size_t)p * 128 + 64 + q];
    const bf16* row = Opart + (size_t)p * 4096 + q * 64 + ds;
    bf16x8 a0 = *(const bf16x8*)row;
    bf16x8 a1 = *(const bf16x8*)(row + 8);
#pragma unroll
    for (int i = 0; i < 8; i++) {
      acc[i]     += wgt * (float)a0[i];
      acc[i + 8] += wgt * (float)a1[i];
    }
  }
  float Linv = 1.0f / L;
  bf16x8 w0, w1;
#pragma unroll
  for (int i = 0; i < 8; i++) {
    w0[i] = (bf16)(acc[i] * Linv);
    w1[i] = (bf16)(acc[i + 8] * Linv);
  }
  bf16* dst = attn + ((size_t)(b * 2048) + qt * 64 + q) * 1024 + h * 64 + ds;
  *(bf16x8*)dst = w0;
  *(bf16x8*)(dst + 8) = w1;
}

// ---------------- launch ----------------
extern "C" void kernel_launch(void* const* d_in, const int* in_sizes, int n_in,
                              void* d_out, int out_size, void* d_ws, size_t ws_size,
                              hipStream_t stream) {
  const float* x     = (const float*)d_in[0];
  const float* Wqkv  = (const float*)d_in[1];
  const float* Wproj = (const float*)d_in[2];
  float* outp = (float*)d_out;
  const int B = 2, T = 2048, C = 1024;
  const int M = B * T;  // 4096

  char* ws = (char*)d_ws;
  size_t off = 0;
  auto alloc = [&](size_t bytes) {
    void* p = ws + off;
    off += (bytes + 255) & ~(size_t)255;
    return p;
  };
  bf16* xb     = (bf16*)alloc((size_t)M * C * 2);        // 8 MB; attn aliases after gemm
  bf16* wprojt = (bf16*)alloc((size_t)C * C * 2);        // 2 MB
  float* cosT  = (float*)alloc((size_t)T * 32 * 4);
  float* sinT  = (float*)alloc((size_t)T * 32 * 4);
  bf16* region = (bf16*)alloc((size_t)M * 3 * C * 2 + (size_t)3 * C * C * 2);  // 30 MB: qkv + wqkvt
  bf16* qkv    = region;                                 // 24 MB; dead after rope_v
  bf16* wqkvt  = region + (size_t)M * 3 * C;             // 6 MB; dead after qkv gemm
  bf16* qr     = (bf16*)alloc((size_t)M * C * 2);
  bf16* kr     = (bf16*)alloc((size_t)M * C * 2);
  bf16* vt     = (bf16*)alloc((size_t)M * C * 2);
  // aliases (lifetimes disjoint, stream-ordered):
  bf16* attn   = xb;                                     // xb dead after qkv gemm
  bf16* Opart  = region;                                 // 26.75 MB (flash runs after rope_v)
  float* ml    = (float*)(region + (size_t)3264 * 4096); // 1.67 MB -> region ends at 28.4 MB

  k_prep<<<dim3(6400), dim3(256), 0, stream>>>(x, xb, cosT, sinT, Wqkv, wqkvt, Wproj, wprojt);
  k_gemm_bt<0><<<dim3(3 * C / 128, M / 128), dim3(256), 0, stream>>>(xb, wqkvt, (float*)nullptr, qkv, M, 3 * C, C);
  k_rope_v<<<dim3(T / 64, 32), dim3(256), 0, stream>>>(qkv, cosT, sinT, qr, kr, vt);
  k_flash_part<<<dim3(3264), dim3(128), 0, stream>>>(qr, kr, vt, Opart, ml, attn);
  k_combine<<<dim3(832), dim3(256), 0, stream>>>(Opart, ml, attn);
  k_gemm_64<<<dim3(C / 128, M / 64), dim3(128), 0, stream>>>(attn, wprojt, outp, M, C, C);
}